// Round 14
// baseline (94.966 us; speedup 1.0000x reference)
//
#include <hip/hip_runtime.h>
#include <hip/hip_bf16.h>

#define S_LEN 2048
#define DH 64
#define LDPK 72    // K rows: 144B (16B-aligned for b128)
#define LDPV 132   // V^T rows: 264B (8B-aligned), 128 cols + 4 pad

typedef __attribute__((ext_vector_type(4)))  float f32x4;
typedef __attribute__((ext_vector_type(16))) float f32x16;
typedef __attribute__((ext_vector_type(8)))  short short8v;
typedef __attribute__((ext_vector_type(4)))  unsigned uint4v;
typedef __attribute__((ext_vector_type(2)))  unsigned uint2v;

__device__ __forceinline__ unsigned cvt_pk(float a, float b) {
    unsigned r;
    asm("v_cvt_pk_bf16_f32 %0, %1, %2" : "=v"(r) : "v"(a), "v"(b));
    return r;
}

__global__ __launch_bounds__(512) void fa_fwd_kernel(
    const float* __restrict__ Q, const float* __restrict__ K,
    const float* __restrict__ V, float* __restrict__ O)
{
    const int tid  = threadIdx.x;
    const int lane = tid & 63;
    const int w    = tid >> 6;           // 0..7
    const int g2   = w >> 2;             // 0: low KV half, 1: high KV half
    const int rt   = w & 3;              // 32-row sub-tile (both groups cover all rows)
    const int bh   = blockIdx.x & 63;    // same-bh blocks 64 apart -> same XCD
    const int qb   = 15 - (blockIdx.x >> 6);   // LPT: heavy tiles dispatch first

    const int nT  = qb + 1;              // intervals (each stages BOTH 64-kv halves)
    const int mid = nT * 64;             // high-half stream base
    const int q0  = qb * 128 + rt * 32;  // wave's first q-row

    const size_t base = (size_t)bh * S_LEN * DH;
    const float* Qg = Q + base;
    const float* Kg = K + base;
    const float* Vg = V + base;
    float*       Og = O + base;

    // K[2][128][72] (36864B) + V^T[2][64][132] (33792B) = 70656B; merge buffer
    // overlays the (dead) K region after the loop.
    __shared__ __align__(16) char smem[70656];
    short (*K_lds)[128][LDPK] = (short(*)[128][LDPK])smem;           // [buf][kv][d]
    short (*V_lds)[DH][LDPV]  = (short(*)[DH][LDPV])(smem + 36864);  // [buf][d][col]
    float (*Mbuf)[64][34]     = (float(*)[64][34])smem;              // [rt][lane][m,l,o]

    const int q  = lane & 31;            // lane's q-column
    const int hi = lane >> 5;            // 0/1: k-slot half
    // staging: 512 threads cover 128 kv-rows (low 64 + high 64) per interval
    const int kr = tid >> 2;             // 0..127: K row (0-63 low, 64-127 high)
    const int dc = (tid & 3) * 16;       // K col 0,16,32,48
    const int vd = tid & 63;             // V col (d)
    const int vg = tid >> 6;             // 0..7: V col-group (0-3 low, 4-7 high)

    unsigned kpfu[8], vpf[8];

    auto prefetch = [&](int s) {
        const int krow = s * 64 + (kr & 63) + (kr >> 6) * mid;
        const float* kp = Kg + (size_t)krow * DH + dc;
        f32x4 a = *(const f32x4*)kp;
        f32x4 b = *(const f32x4*)(kp + 4);
        f32x4 c = *(const f32x4*)(kp + 8);
        f32x4 d = *(const f32x4*)(kp + 12);
        kpfu[0] = cvt_pk(a[0], a[1]); kpfu[1] = cvt_pk(a[2], a[3]);
        kpfu[2] = cvt_pk(b[0], b[1]); kpfu[3] = cvt_pk(b[2], b[3]);
        kpfu[4] = cvt_pk(c[0], c[1]); kpfu[5] = cvt_pk(c[2], c[3]);
        kpfu[6] = cvt_pk(d[0], d[1]); kpfu[7] = cvt_pk(d[2], d[3]);
        #pragma unroll
        for (int i = 0; i < 8; ++i) {
            int col  = vg * 16 + i * 2;                     // 0..127
            int vrow = s * 64 + (col & 63) + (col >> 6) * mid;
            float x = Vg[(size_t)vrow * DH + vd];
            float y = Vg[(size_t)(vrow + 1) * DH + vd];
            vpf[i] = cvt_pk(x, y);
        }
    };

    auto stage = [&](int b) {
        uint4v u0 = {kpfu[0], kpfu[1], kpfu[2], kpfu[3]};
        uint4v u1 = {kpfu[4], kpfu[5], kpfu[6], kpfu[7]};
        *(uint4v*)&K_lds[b][kr][dc]     = u0;   // ds_write_b128
        *(uint4v*)&K_lds[b][kr][dc + 8] = u1;
        #pragma unroll
        for (int i = 0; i < 8; ++i) {
            int col = vg * 16 + i * 2;
            *(unsigned*)&V_lds[b][vd][col] = vpf[i];
        }
    };

    const float qscale = 0.125f * 1.44269504088896340736f;

    // ---- Q B-fragments: lane supplies Q[d = ds*16 + hi*8 + j][q0+q], scaled ----
    short8v qfrag[4];
    #pragma unroll
    for (int ds = 0; ds < 4; ++ds) {
        const float* qp = Qg + (size_t)(q0 + q) * DH + ds * 16 + hi * 8;
        f32x4 a = *(const f32x4*)qp;
        f32x4 b = *(const f32x4*)(qp + 4);
        uint4v u;
        u[0] = cvt_pk(a[0] * qscale, a[1] * qscale);
        u[1] = cvt_pk(a[2] * qscale, a[3] * qscale);
        u[2] = cvt_pk(b[0] * qscale, b[1] * qscale);
        u[3] = cvt_pk(b[2] * qscale, b[3] * qscale);
        qfrag[ds] = __builtin_bit_cast(short8v, u);
    }

    f32x16 o_acc[2];   // O^T[dt*32 + rowmap][q]
    o_acc[0] = (f32x16)(0.f);
    o_acc[1] = (f32x16)(0.f);
    float m_run = -1e30f, l_run = 0.f;

    prefetch(0);
    stage(0);
    int cur = 0;
    __syncthreads();

    #pragma unroll 1
    for (int s = 0; s < nT; ++s) {
        const bool have = (s + 1) < nT;
        if (have) prefetch(s + 1);       // global->reg, lands under compute

        const int kvb_eff = g2 * mid + s * 64;   // this group's kv base
        if (kvb_eff <= q0) {
            const short (*Kc)[LDPK] = (const short(*)[LDPK])&K_lds[cur][g2 * 64];
            const char* Vc = (const char*)&V_lds[cur][0][0];
            const int vco = g2 * 64;     // V column offset for this group

            // ---- swapped QK^T: S^T[kv][q] = K·Q^T, two 32-kv tiles ----
            f32x16 s_acc[2];
            s_acc[0] = (f32x16)(0.f);
            s_acc[1] = (f32x16)(0.f);

            __builtin_amdgcn_s_setprio(1);
            #pragma unroll
            for (int ds = 0; ds < 4; ++ds) {
                #pragma unroll
                for (int kt = 0; kt < 2; ++kt) {
                    short8v kf = *(const short8v*)&Kc[kt * 32 + q][ds * 16 + hi * 8];
                    s_acc[kt] = __builtin_amdgcn_mfma_f32_32x32x16_bf16(
                        kf, qfrag[ds], s_acc[kt], 0, 0, 0);
                }
            }
            __builtin_amdgcn_s_setprio(0);

            // ---- causal mask (diagonal sub-tiles only) ----
            const int qrow = q0 + q;
            if (kvb_eff + 63 > q0) {
                #pragma unroll
                for (int kt = 0; kt < 2; ++kt)
                    #pragma unroll
                    for (int r = 0; r < 16; ++r) {
                        int kv = kvb_eff + kt * 32 + (r & 3) + 8 * (r >> 2) + 4 * hi;
                        if (kv > qrow) s_acc[kt][r] = -1e30f;
                    }
            }

            // ---- softmax: in-lane + one shfl_xor(32); defer-max THR=8 ----
            float tl = -1e30f;
            #pragma unroll
            for (int kt = 0; kt < 2; ++kt)
                #pragma unroll
                for (int r = 0; r < 16; ++r)
                    tl = fmaxf(tl, s_acc[kt][r]);
            float tmax = fmaxf(tl, __shfl_xor(tl, 32));

            if (!__all(tmax <= m_run + 8.0f)) {
                float mnew = fmaxf(m_run, tmax);
                float corr = __builtin_amdgcn_exp2f(m_run - mnew);
                m_run = mnew;
                l_run *= corr;
                #pragma unroll
                for (int dt = 0; dt < 2; ++dt)
                    #pragma unroll
                    for (int r = 0; r < 16; ++r)
                        o_acc[dt][r] *= corr;   // in-lane: o col == lane's q
            }

            float rsum = 0.f;
            #pragma unroll
            for (int kt = 0; kt < 2; ++kt)
                #pragma unroll
                for (int r = 0; r < 16; ++r) {
                    float pe = __builtin_amdgcn_exp2f(s_acc[kt][r] - m_run);
                    s_acc[kt][r] = pe;
                    rsum += pe;
                }
            rsum += __shfl_xor(rsum, 32);
            l_run += rsum;

            // ---- pack P; registers land in B-frag k-slot order ----
            unsigned pk_[2][8];
            #pragma unroll
            for (int kt = 0; kt < 2; ++kt)
                #pragma unroll
                for (int m = 0; m < 8; ++m)
                    pk_[kt][m] = cvt_pk(s_acc[kt][2 * m], s_acc[kt][2 * m + 1]);

            // ---- PV: O^T += V^T · P ----
            __builtin_amdgcn_s_setprio(1);
            #pragma unroll
            for (int ss = 0; ss < 4; ++ss) {
                const int kt = ss >> 1, bofs = 4 * (ss & 1);
                uint4v bu = {pk_[kt][bofs], pk_[kt][bofs + 1],
                             pk_[kt][bofs + 2], pk_[kt][bofs + 3]};
                short8v pb = __builtin_bit_cast(short8v, bu);
                #pragma unroll
                for (int dt = 0; dt < 2; ++dt) {
                    const char* vrow = Vc + (size_t)(dt * 32 + q) * (LDPV * 2);
                    uint2v lo = *(const uint2v*)(vrow + (vco + 16 * ss + 4 * hi) * 2);
                    uint2v h2 = *(const uint2v*)(vrow + (vco + 16 * ss + 8 + 4 * hi) * 2);
                    uint4v au = {lo[0], lo[1], h2[0], h2[1]};
                    short8v va = __builtin_bit_cast(short8v, au);
                    o_acc[dt] = __builtin_amdgcn_mfma_f32_32x32x16_bf16(
                        va, pb, o_acc[dt], 0, 0, 0);
                }
            }
            __builtin_amdgcn_s_setprio(0);
        }

        if (have) {
            stage(cur ^ 1);
            __syncthreads();
        }
        cur ^= 1;
    }

    // ---- merge the two kv-half partials per row (all in-lane; LDS overlay) ----
    __syncthreads();                     // all compute done before overlaying K
    if (g2 == 1) {
        float* mb = Mbuf[rt][lane];
        mb[0] = m_run;
        mb[1] = l_run;
        #pragma unroll
        for (int dt = 0; dt < 2; ++dt)
            #pragma unroll
            for (int r = 0; r < 16; ++r)
                mb[2 + dt * 16 + r] = o_acc[dt][r];
    }
    __syncthreads();
    if (g2 == 0) {
        const float* mb = Mbuf[rt][lane];
        float mB = mb[0], lB = mb[1];
        float mN = fmaxf(m_run, mB);
        float sA = __builtin_amdgcn_exp2f(m_run - mN);   // A = low half, never empty
        float sB = __builtin_amdgcn_exp2f(mB - mN);      // 0 if B empty
        float inv = 1.0f / (l_run * sA + lB * sB);
        float* orow = Og + (size_t)(q0 + q) * DH;
        #pragma unroll
        for (int dt = 0; dt < 2; ++dt) {
            #pragma unroll
            for (int g4 = 0; g4 < 4; ++g4) {
                f32x4 ov;
                #pragma unroll
                for (int i2 = 0; i2 < 4; ++i2)
                    ov[i2] = (o_acc[dt][4 * g4 + i2] * sA +
                              mb[2 + dt * 16 + 4 * g4 + i2] * sB) * inv;
                *(f32x4*)(orow + dt * 32 + 8 * g4 + 4 * hi) = ov;
            }
        }
    }
}

extern "C" void kernel_launch(void* const* d_in, const int* in_sizes, int n_in,
                              void* d_out, int out_size, void* d_ws, size_t ws_size,
                              hipStream_t stream) {
    const float* q = (const float*)d_in[0];
    const float* k = (const float*)d_in[1];
    const float* v = (const float*)d_in[2];
    float* out = (float*)d_out;
    // 1024 blocks x 512 threads: 64 (b,h) x 16 q-tiles, qb-descending (LPT).
    // Each block: one q-tile, 2-way in-block KV split, in-LDS merge.
    fa_fwd_kernel<<<dim3(1024), dim3(512), 0, stream>>>(q, k, v, out);
}

// Round 15
// 81.250 us; speedup vs baseline: 1.1688x; 1.1688x over previous
//
#include <hip/hip_runtime.h>
#include <hip/hip_bf16.h>

#define S_LEN 2048
#define DH 64
#define QBLK 128
#define KVBLK 64
#define LDPK 72   // K rows: 144B (16B-aligned)
#define LDPV 68   // V^T rows: 136B (8B-aligned)

typedef __attribute__((ext_vector_type(4)))  float f32x4;
typedef __attribute__((ext_vector_type(16))) float f32x16;
typedef __attribute__((ext_vector_type(8)))  short short8v;
typedef __attribute__((ext_vector_type(4)))  unsigned uint4v;
typedef __attribute__((ext_vector_type(2)))  unsigned uint2v;

__device__ __forceinline__ unsigned cvt_pk(float a, float b) {
    unsigned r;
    asm("v_cvt_pk_bf16_f32 %0, %1, %2" : "=v"(r) : "v"(a), "v"(b));
    return r;
}

__global__ __launch_bounds__(512) void fa_fwd_kernel(
    const float* __restrict__ Q, const float* __restrict__ K,
    const float* __restrict__ V, float* __restrict__ O)
{
    const int tid  = threadIdx.x;
    const int lane = tid & 63;
    const int w    = tid >> 6;          // 0..7 waves
    const int bh   = blockIdx.x & 63;   // same-bh blocks 64 apart -> same XCD
    const int p    = blockIdx.x >> 6;   // 0..7

    // concurrent pair: waves 0-3 -> q-tile (15-p), waves 4-7 -> q-tile p;
    // one monotonic KV stream [0, (16-p)*128). Past-extent waves stay producers.
    const int qb = (w < 4) ? (15 - p) : p;
    const int q0 = qb * QBLK + (w & 3) * 32;      // wave's first q-row
    const int kv_end = (16 - p) * QBLK;           // stream extent
    const int T = kv_end >> 6;                    // 64-kv intervals; ALWAYS EVEN

    const size_t base = (size_t)bh * S_LEN * DH;
    const float* Qg = Q + base;
    const float* Kg = K + base;
    const float* Vg = V + base;
    float*       Og = O + base;

    __shared__ __align__(16) short K_lds[2][KVBLK][LDPK];   // [buf][kv][d]
    __shared__ __align__(16) short V_lds[2][DH][LDPV];      // [buf][d][kv]

    const int q  = lane & 31;           // lane's q-column within the wave tile
    const int hi = lane >> 5;           // 0/1: k-slot half
    // staging decomposition (512 threads cover the 64x64 tile once)
    const int kr = tid >> 3;            // K row 0..63
    const int dc = (tid & 7) * 8;       // K col 0,8,...,56
    const int vd = tid & 63;            // V col (d)
    const int vg = tid >> 6;            // V row-group 0..7

    // 2-deep load pipeline: raw f32 register sets A/B (static names, rule #20).
    // Convert happens at stage time, one full interval after issue -> vmcnt ~0.
    f32x4 kA0, kA1, kB0, kB1;
    float vA[8], vB[8];

    auto issueA = [&](int kvb) {
        const float* kp = Kg + (size_t)(kvb + kr) * DH + dc;
        kA0 = *(const f32x4*)kp;
        kA1 = *(const f32x4*)(kp + 4);
        #pragma unroll
        for (int i = 0; i < 4; ++i) {
            int kv = vg * 8 + i * 2;
            vA[2 * i]     = Vg[(size_t)(kvb + kv) * DH + vd];
            vA[2 * i + 1] = Vg[(size_t)(kvb + kv + 1) * DH + vd];
        }
    };
    auto issueB = [&](int kvb) {
        const float* kp = Kg + (size_t)(kvb + kr) * DH + dc;
        kB0 = *(const f32x4*)kp;
        kB1 = *(const f32x4*)(kp + 4);
        #pragma unroll
        for (int i = 0; i < 4; ++i) {
            int kv = vg * 8 + i * 2;
            vB[2 * i]     = Vg[(size_t)(kvb + kv) * DH + vd];
            vB[2 * i + 1] = Vg[(size_t)(kvb + kv + 1) * DH + vd];
        }
    };
    auto stageA = [&](int b) {
        uint4v u = {cvt_pk(kA0[0], kA0[1]), cvt_pk(kA0[2], kA0[3]),
                    cvt_pk(kA1[0], kA1[1]), cvt_pk(kA1[2], kA1[3])};
        *(uint4v*)&K_lds[b][kr][dc] = u;   // ds_write_b128
        #pragma unroll
        for (int i = 0; i < 4; ++i) {
            int kv = vg * 8 + i * 2;
            *(unsigned*)((char*)&V_lds[b][0][0] + vd * (LDPV * 2) + kv * 2) =
                cvt_pk(vA[2 * i], vA[2 * i + 1]);
        }
    };
    auto stageB = [&](int b) {
        uint4v u = {cvt_pk(kB0[0], kB0[1]), cvt_pk(kB0[2], kB0[3]),
                    cvt_pk(kB1[0], kB1[1]), cvt_pk(kB1[2], kB1[3])};
        *(uint4v*)&K_lds[b][kr][dc] = u;
        #pragma unroll
        for (int i = 0; i < 4; ++i) {
            int kv = vg * 8 + i * 2;
            *(unsigned*)((char*)&V_lds[b][0][0] + vd * (LDPV * 2) + kv * 2) =
                cvt_pk(vB[2 * i], vB[2 * i + 1]);
        }
    };

    const float qscale = 0.125f * 1.44269504088896340736f;

    // ---- Q B-fragments: lane supplies Q[d = ds*16 + hi*8 + j][q0+q], scaled ----
    short8v qfrag[4];
    #pragma unroll
    for (int ds = 0; ds < 4; ++ds) {
        const float* qp = Qg + (size_t)(q0 + q) * DH + ds * 16 + hi * 8;
        f32x4 a = *(const f32x4*)qp;
        f32x4 b = *(const f32x4*)(qp + 4);
        uint4v u;
        u[0] = cvt_pk(a[0] * qscale, a[1] * qscale);
        u[1] = cvt_pk(a[2] * qscale, a[3] * qscale);
        u[2] = cvt_pk(b[0] * qscale, b[1] * qscale);
        u[3] = cvt_pk(b[2] * qscale, b[3] * qscale);
        qfrag[ds] = __builtin_bit_cast(short8v, u);
    }

    f32x16 o_acc[2];   // O^T[dt*32 + rowmap][q]
    o_acc[0] = (f32x16)(0.f);
    o_acc[1] = (f32x16)(0.f);
    float m_run = -1e30f, l_run = 0.f;

    // verified 32x32 in-lane-softmax compute body for one 64-kv tile
    auto computeTile = [&](int cur, int kvb) {
        const short (*Kc)[LDPK] = K_lds[cur];
        const char* Vc = (const char*)&V_lds[cur][0][0];

        f32x16 s_acc[2];
        s_acc[0] = (f32x16)(0.f);
        s_acc[1] = (f32x16)(0.f);

        __builtin_amdgcn_s_setprio(1);
        #pragma unroll
        for (int ds = 0; ds < 4; ++ds) {
            #pragma unroll
            for (int kt = 0; kt < 2; ++kt) {
                short8v kf = *(const short8v*)&Kc[kt * 32 + q][ds * 16 + hi * 8];
                s_acc[kt] = __builtin_amdgcn_mfma_f32_32x32x16_bf16(
                    kf, qfrag[ds], s_acc[kt], 0, 0, 0);
            }
        }
        __builtin_amdgcn_s_setprio(0);

        const int qrow = q0 + q;
        if (kvb + KVBLK - 1 > q0) {
            #pragma unroll
            for (int kt = 0; kt < 2; ++kt)
                #pragma unroll
                for (int r = 0; r < 16; ++r) {
                    int kv = kvb + kt * 32 + (r & 3) + 8 * (r >> 2) + 4 * hi;
                    if (kv > qrow) s_acc[kt][r] = -1e30f;
                }
        }

        float tl = -1e30f;
        #pragma unroll
        for (int kt = 0; kt < 2; ++kt)
            #pragma unroll
            for (int r = 0; r < 16; ++r)
                tl = fmaxf(tl, s_acc[kt][r]);
        float tmax = fmaxf(tl, __shfl_xor(tl, 32));

        if (!__all(tmax <= m_run + 8.0f)) {
            float mnew = fmaxf(m_run, tmax);
            float corr = __builtin_amdgcn_exp2f(m_run - mnew);
            m_run = mnew;
            l_run *= corr;
            #pragma unroll
            for (int dt = 0; dt < 2; ++dt)
                #pragma unroll
                for (int r = 0; r < 16; ++r)
                    o_acc[dt][r] *= corr;   // in-lane: o col == this lane's q
        }

        float rsum = 0.f;
        #pragma unroll
        for (int kt = 0; kt < 2; ++kt)
            #pragma unroll
            for (int r = 0; r < 16; ++r) {
                float pe = __builtin_amdgcn_exp2f(s_acc[kt][r] - m_run);
                s_acc[kt][r] = pe;
                rsum += pe;
            }
        rsum += __shfl_xor(rsum, 32);
        l_run += rsum;

        unsigned pk_[2][8];
        #pragma unroll
        for (int kt = 0; kt < 2; ++kt)
            #pragma unroll
            for (int m = 0; m < 8; ++m)
                pk_[kt][m] = cvt_pk(s_acc[kt][2 * m], s_acc[kt][2 * m + 1]);

        __builtin_amdgcn_s_setprio(1);
        #pragma unroll
        for (int ss = 0; ss < 4; ++ss) {
            const int kt = ss >> 1, bofs = 4 * (ss & 1);
            uint4v bu = {pk_[kt][bofs], pk_[kt][bofs + 1],
                         pk_[kt][bofs + 2], pk_[kt][bofs + 3]};
            short8v pb = __builtin_bit_cast(short8v, bu);
            #pragma unroll
            for (int dt = 0; dt < 2; ++dt) {
                const char* vrow = Vc + (size_t)(dt * 32 + q) * (LDPV * 2);
                uint2v lo = *(const uint2v*)(vrow + (16 * ss + 4 * hi) * 2);
                uint2v h2 = *(const uint2v*)(vrow + (16 * ss + 8 + 4 * hi) * 2);
                uint4v au = {lo[0], lo[1], h2[0], h2[1]};
                short8v va = __builtin_bit_cast(short8v, au);
                o_acc[dt] = __builtin_amdgcn_mfma_f32_32x32x16_bf16(
                    va, pb, o_acc[dt], 0, 0, 0);
            }
        }
        __builtin_amdgcn_s_setprio(0);
    };

    // prologue: issue 0->A and 1->B; stage 0 (waits only on A's loads)
    issueA(0);
    if (T > 1) issueB(64);
    stageA(0);
    int cur = 0;
    __syncthreads();

    #pragma unroll 1
    for (int s = 0; s < T; s += 2) {
        // even interval s: compute(s) from cur; stage s+1 (B, issued last interval);
        // issue s+2 into A (free since stage(s) consumed it).
        if (s + 2 < T) issueA((s + 2) * 64);
        if (s * 64 <= q0) computeTile(cur, s * 64);
        if (s + 1 < T) {
            stageB(cur ^ 1);
            __syncthreads();
        }
        cur ^= 1;

        // odd interval s+1
        if (s + 3 < T) issueB((s + 3) * 64);
        if ((s + 1) * 64 <= q0) computeTile(cur, (s + 1) * 64);
        if (s + 2 < T) {
            stageA(cur ^ 1);
            __syncthreads();
        }
        cur ^= 1;
    }

    // ---- epilogue: all in-lane; O[q][d], d = dt*32 + 8g + 4hi + i ----
    float inv = 1.0f / l_run;
    float* orow = Og + (size_t)(q0 + q) * DH;
    #pragma unroll
    for (int dt = 0; dt < 2; ++dt) {
        #pragma unroll
        for (int g = 0; g < 4; ++g) {
            f32x4 ov = {o_acc[dt][4 * g] * inv,     o_acc[dt][4 * g + 1] * inv,
                        o_acc[dt][4 * g + 2] * inv, o_acc[dt][4 * g + 3] * inv};
            *(f32x4*)(orow + dt * 32 + 8 * g + 4 * hi) = ov;
        }
    }
}

extern "C" void kernel_launch(void* const* d_in, const int* in_sizes, int n_in,
                              void* d_out, int out_size, void* d_ws, size_t ws_size,
                              hipStream_t stream) {
    const float* q = (const float*)d_in[0];
    const float* k = (const float*)d_in[1];
    const float* v = (const float*)d_in[2];
    float* out = (float*)d_out;
    // 512 blocks x 512 threads: 64 (b,h) x 8 concurrent pairs {15-p, p}; 16 waves/CU
    fa_fwd_kernel<<<dim3(512), dim3(512), 0, stream>>>(q, k, v, out);
}

// Round 16
// 75.957 us; speedup vs baseline: 1.2503x; 1.0697x over previous
//
#include <hip/hip_runtime.h>
#include <hip/hip_bf16.h>

#define S_LEN 2048
#define DH 64
#define QBLK 128
#define KVBLK 64
#define LDPK 72   // K rows: 144B (16B-aligned)
#define LDPV 72   // V^T rows: 144B (16B-aligned for b128 frag reads)

typedef __attribute__((ext_vector_type(4)))  float f32x4;
typedef __attribute__((ext_vector_type(16))) float f32x16;
typedef __attribute__((ext_vector_type(8)))  short short8v;
typedef __attribute__((ext_vector_type(4)))  unsigned uint4v;
typedef __attribute__((ext_vector_type(2)))  unsigned uint2v;

__device__ __forceinline__ unsigned cvt_pk(float a, float b) {
    unsigned r;
    asm("v_cvt_pk_bf16_f32 %0, %1, %2" : "=v"(r) : "v"(a), "v"(b));
    return r;
}

// column permutation: LDS col c holds V^T row kv such that a single b128 read
// at col 16ss+8hi yields the A-frag k-slots j=0..7 (kv = 16ss+(j&3)+8(j>>2)+4hi)
__device__ __forceinline__ int vcol(int kv) {
    int ss = kv >> 4, w16 = kv & 15;
    int hi = (w16 >> 2) & 1;
    int m  = w16 - 4 * hi;
    int j  = (m & 3) + 4 * (m >> 3);
    return ss * 16 + hi * 8 + j;
}

__global__ __launch_bounds__(512) void fa_fwd_kernel(
    const float* __restrict__ Q, const float* __restrict__ K,
    const float* __restrict__ V, float* __restrict__ O)
{
    const int tid  = threadIdx.x;
    const int lane = tid & 63;
    const int w    = tid >> 6;          // 0..7 waves
    // CU-balance remap: under round-robin dispatch, bid and bid+256 co-reside on
    // one CU; give them pair-indices p and 7-p -> per-CU total = 25 intervals
    // uniformly. Same-bh blocks stay 32*k apart -> same XCD (L2 sharing kept).
    const int bid  = blockIdx.x;
    const int lo8  = (bid >> 5) & 7;
    const int p    = (bid < 256) ? lo8 : 7 - lo8;
    const int bh   = (bid & 31) | ((bid >> 8) << 5);

    // concurrent pair: waves 0-3 -> q-tile (15-p), waves 4-7 -> q-tile p;
    // one monotonic KV stream [0, (16-p)*128). Past-extent waves stay producers.
    const int qb = (w < 4) ? (15 - p) : p;
    const int q0 = qb * QBLK + (w & 3) * 32;      // wave's first q-row
    const int kv_end = (16 - p) * QBLK;           // stream extent

    const size_t base = (size_t)bh * S_LEN * DH;
    const float* Qg = Q + base;
    const float* Kg = K + base;
    const float* Vg = V + base;
    float*       Og = O + base;

    __shared__ __align__(16) short K_lds[2][KVBLK][LDPK];   // [buf][kv][d]
    __shared__ __align__(16) short V_lds[2][DH][LDPV];      // [buf][d][permuted col]

    const int q  = lane & 31;           // lane's q-column within the wave tile
    const int hi = lane >> 5;           // 0/1: k-slot half
    // staging decomposition (512 threads cover the 64x64 tile once)
    const int kr = tid >> 3;            // K row 0..63
    const int dc = (tid & 7) * 8;       // K col 0,8,...,56
    const int vd = tid & 63;            // V col (d)
    const int vg = tid >> 6;            // V row-group 0..7
    const int c0 = vcol(vg * 8);        // permuted cols for this thread's 2 4-groups
    const int c1 = vcol(vg * 8 + 4);

    unsigned kpfu[4], vpf[4];

    auto prefetch = [&](int kvb) {
        const float* kp = Kg + (size_t)(kvb + kr) * DH + dc;
        f32x4 a = *(const f32x4*)kp;
        f32x4 b = *(const f32x4*)(kp + 4);
        kpfu[0] = cvt_pk(a[0], a[1]); kpfu[1] = cvt_pk(a[2], a[3]);
        kpfu[2] = cvt_pk(b[0], b[1]); kpfu[3] = cvt_pk(b[2], b[3]);
        #pragma unroll
        for (int i = 0; i < 4; ++i) {
            int kv = vg * 8 + i * 2;
            float x = Vg[(size_t)(kvb + kv) * DH + vd];
            float y = Vg[(size_t)(kvb + kv + 1) * DH + vd];
            vpf[i] = cvt_pk(x, y);
        }
    };

    auto stage = [&](int b) {
        uint4v u = {kpfu[0], kpfu[1], kpfu[2], kpfu[3]};
        *(uint4v*)&K_lds[b][kr][dc] = u;                 // ds_write_b128
        uint2v v0 = {vpf[0], vpf[1]};
        uint2v v1 = {vpf[2], vpf[3]};
        *(uint2v*)&V_lds[b][vd][c0] = v0;                // ds_write_b64, bank-clean
        *(uint2v*)&V_lds[b][vd][c1] = v1;
    };

    const float qscale = 0.125f * 1.44269504088896340736f;

    // ---- Q B-fragments: lane supplies Q[d = ds*16 + hi*8 + j][q0+q], scaled ----
    short8v qfrag[4];
    #pragma unroll
    for (int ds = 0; ds < 4; ++ds) {
        const float* qp = Qg + (size_t)(q0 + q) * DH + ds * 16 + hi * 8;
        f32x4 a = *(const f32x4*)qp;
        f32x4 b = *(const f32x4*)(qp + 4);
        uint4v u;
        u[0] = cvt_pk(a[0] * qscale, a[1] * qscale);
        u[1] = cvt_pk(a[2] * qscale, a[3] * qscale);
        u[2] = cvt_pk(b[0] * qscale, b[1] * qscale);
        u[3] = cvt_pk(b[2] * qscale, b[3] * qscale);
        qfrag[ds] = __builtin_bit_cast(short8v, u);
    }

    f32x16 o_acc[2];   // O^T[dt*32 + rowmap][q]
    o_acc[0] = (f32x16)(0.f);
    o_acc[1] = (f32x16)(0.f);
    float m_run = -1e30f, l_run = 0.f;

    prefetch(0);
    stage(0);
    int cur = 0;
    __syncthreads();

    #pragma unroll 1
    for (int kvb = 0; kvb < kv_end; kvb += KVBLK) {
        int nkv = kvb + KVBLK;
        const bool have = nkv < kv_end;
        if (have) prefetch(nkv);   // global->reg, lands under compute

        if (kvb <= q0) {           // this wave still inside its causal extent
            const short (*Kc)[LDPK] = K_lds[cur];
            const char* Vc = (const char*)&V_lds[cur][0][0];

            // ---- swapped QK^T: S^T[kv][q] = K·Q^T, two 32-kv tiles ----
            f32x16 s_acc[2];
            s_acc[0] = (f32x16)(0.f);
            s_acc[1] = (f32x16)(0.f);

            __builtin_amdgcn_s_setprio(1);
            #pragma unroll
            for (int ds = 0; ds < 4; ++ds) {
                #pragma unroll
                for (int kt = 0; kt < 2; ++kt) {
                    short8v kf = *(const short8v*)&Kc[kt * 32 + q][ds * 16 + hi * 8];
                    s_acc[kt] = __builtin_amdgcn_mfma_f32_32x32x16_bf16(
                        kf, qfrag[ds], s_acc[kt], 0, 0, 0);
                }
            }
            __builtin_amdgcn_s_setprio(0);

            // ---- mask (diagonal tiles only): kv = kvb+32kt+(r&3)+8(r>>2)+4hi ----
            const int qrow = q0 + q;
            if (kvb + KVBLK - 1 > q0) {
                #pragma unroll
                for (int kt = 0; kt < 2; ++kt)
                    #pragma unroll
                    for (int r = 0; r < 16; ++r) {
                        int kv = kvb + kt * 32 + (r & 3) + 8 * (r >> 2) + 4 * hi;
                        if (kv > qrow) s_acc[kt][r] = -1e30f;
                    }
            }

            // ---- softmax: TREE max (depth 5, not 31-chain) + one shfl_xor(32) ----
            float pm[16];
            #pragma unroll
            for (int r = 0; r < 16; ++r)
                pm[r] = fmaxf(s_acc[0][r], s_acc[1][r]);
            #pragma unroll
            for (int st = 8; st >= 1; st >>= 1)
                #pragma unroll
                for (int r = 0; r < st; ++r)
                    pm[r] = fmaxf(pm[r], pm[r + st]);
            float tmax = fmaxf(pm[0], __shfl_xor(pm[0], 32));

            if (!__all(tmax <= m_run + 8.0f)) {
                float mnew = fmaxf(m_run, tmax);
                float corr = __builtin_amdgcn_exp2f(m_run - mnew);
                m_run = mnew;
                l_run *= corr;
                #pragma unroll
                for (int dt = 0; dt < 2; ++dt)
                    #pragma unroll
                    for (int r = 0; r < 16; ++r)
                        o_acc[dt][r] *= corr;   // in-lane: o col == this lane's q
            }

            // ---- exp + TREE sum ----
            float ps[16];
            #pragma unroll
            for (int r = 0; r < 16; ++r) {
                float a = __builtin_amdgcn_exp2f(s_acc[0][r] - m_run);
                float b = __builtin_amdgcn_exp2f(s_acc[1][r] - m_run);
                s_acc[0][r] = a;
                s_acc[1][r] = b;
                ps[r] = a + b;
            }
            #pragma unroll
            for (int st = 8; st >= 1; st >>= 1)
                #pragma unroll
                for (int r = 0; r < st; ++r)
                    ps[r] += ps[r + st];
            l_run += ps[0] + __shfl_xor(ps[0], 32);

            // ---- pack P to bf16; registers land directly in B-frag k-slot order ----
            unsigned pk_[2][8];
            #pragma unroll
            for (int kt = 0; kt < 2; ++kt)
                #pragma unroll
                for (int m = 0; m < 8; ++m)
                    pk_[kt][m] = cvt_pk(s_acc[kt][2 * m], s_acc[kt][2 * m + 1]);

            // ---- PV: O^T += V^T · P ; A-frag = ONE b128 read (permuted layout) ----
            __builtin_amdgcn_s_setprio(1);
            #pragma unroll
            for (int s = 0; s < 4; ++s) {
                const int kt = s >> 1, bofs = 4 * (s & 1);
                uint4v bu = {pk_[kt][bofs], pk_[kt][bofs + 1],
                             pk_[kt][bofs + 2], pk_[kt][bofs + 3]};
                short8v pb = __builtin_bit_cast(short8v, bu);
                #pragma unroll
                for (int dt = 0; dt < 2; ++dt) {
                    short8v va = *(const short8v*)(Vc +
                        (size_t)(dt * 32 + q) * (LDPV * 2) + (16 * s + 8 * hi) * 2);
                    o_acc[dt] = __builtin_amdgcn_mfma_f32_32x32x16_bf16(
                        va, pb, o_acc[dt], 0, 0, 0);
                }
            }
            __builtin_amdgcn_s_setprio(0);
        }

        if (have) {
            stage(cur ^ 1);
            __syncthreads();
        }
        cur ^= 1;
    }

    // ---- epilogue: all in-lane; O[q][d], d = dt*32 + 8g + 4hi + i ----
    float inv = 1.0f / l_run;
    float* orow = Og + (size_t)(q0 + q) * DH;
    #pragma unroll
    for (int dt = 0; dt < 2; ++dt) {
        #pragma unroll
        for (int g = 0; g < 4; ++g) {
            f32x4 ov = {o_acc[dt][4 * g] * inv,     o_acc[dt][4 * g + 1] * inv,
                        o_acc[dt][4 * g + 2] * inv, o_acc[dt][4 * g + 3] * inv};
            *(f32x4*)(orow + dt * 32 + 8 * g + 4 * hi) = ov;
        }
    }
}

extern "C" void kernel_launch(void* const* d_in, const int* in_sizes, int n_in,
                              void* d_out, int out_size, void* d_ws, size_t ws_size,
                              hipStream_t stream) {
    const float* q = (const float*)d_in[0];
    const float* k = (const float*)d_in[1];
    const float* v = (const float*)d_in[2];
    float* out = (float*)d_out;
    // 512 blocks x 512 threads: 64 (b,h) x 8 concurrent pairs; CU-balanced remap
    fa_fwd_kernel<<<dim3(512), dim3(512), 0, stream>>>(q, k, v, out);
}